// Round 6
// baseline (889.324 us; speedup 1.0000x reference)
//
#include <hip/hip_runtime.h>
#include <cstdint>

// N=100000 nodes, E=1.6M edges, D=32, 5D=160, ATTR=33
constexpr int D      = 32;
constexpr int FD     = 160;
constexpr int ATTRD  = 33;
constexpr int WTILE  = 16;    // edges per wave (fully independent waves, no barriers)
constexpr int BLOCK  = 256;   // 4 waves/block, wave w -> tile blockIdx*4+w
constexpr int NKS    = 5;     // K-steps of 32 for the 160-K GEMMs
constexpr int ASTR   = 168;   // X2 row stride (shorts): 336 B, 16B-aligned b128, 2-way banks
constexpr int WREGS  = WTILE * ASTR;  // 2688 shorts per-wave union region

typedef __attribute__((ext_vector_type(8))) short short8;  // 8 bf16 (4 VGPRs) MFMA A/B frag
typedef __attribute__((ext_vector_type(4))) float f32x4;   // MFMA C/D frag

__device__ __forceinline__ float fast_tanh(float x) {
    float e = __expf(2.0f * x);
    return 1.0f - 2.0f * __builtin_amdgcn_rcpf(e + 1.0f);
}
// RNE bf16 (ties handled) — used in one-time prep only
__device__ __forceinline__ unsigned short bf16rne(float x) {
    union { float f; unsigned u; } v; v.f = x;
    unsigned r = v.u + 0x7fffu + ((v.u >> 16) & 1u);
    return (unsigned short)(r >> 16);
}
// round-half-up bf16: 2 VALU ops; differs from RNE only at exact ties (<=1 ulp)
__device__ __forceinline__ unsigned short bf16h(float x) {
    union { float f; unsigned u; } v; v.f = x;
    return (unsigned short)((v.u + 0x8000u) >> 16);
}
__device__ __forceinline__ float bf16tof(unsigned short u) {
    union { unsigned u; float f; } v; v.u = ((unsigned)u) << 16;
    return v.f;
}

// Pack Wd1 (160x160) and W1 rows 0..31 (32x32) into bf16 B-fragment lane order.
// B-chunk (nt,ks): lane L holds B[ks*32 + (L>>4)*8 + j][nt*16 + (L&15)], j<8.
// ws layout (shorts): [0, 25600) Wd1 frags; [25600, 26624) W1 frags (K=32).
// W1 row 32 is applied as a rank-1 VALU correction in the kernel.
__global__ void prep_weights(const float* __restrict__ Wd1,
                             const float* __restrict__ W1,
                             unsigned short* __restrict__ wsb) {
    int t = blockIdx.x * blockDim.x + threadIdx.x;
    if (t < FD * FD) {
        int k = t / FD, n = t - k * FD;
        int nt = n >> 4, l15 = n & 15;
        int ks = k >> 5, quad = (k >> 3) & 3, j = k & 7;
        int dst = ((nt * NKS + ks) * 64 + quad * 16 + l15) * 8 + j;
        wsb[dst] = bf16rne(Wd1[t]);
    } else if (t < FD * FD + 32 * D) {
        int t2 = t - FD * FD;            // t2 = k*32 + n, k in [0,32)
        int k = t2 >> 5, n = t2 & 31;
        int nt = n >> 4, l15 = n & 15;
        int quad = k >> 3, j = k & 7;
        int dst = FD * FD + (nt * 64 + quad * 16 + l15) * 8 + j;
        wsb[dst] = bf16rne(W1[k * D + n]);
    }
}

// (256,4): VGPR cap 128 ((256,8) spilled in R3: 3.6 GB HBM). Zero __syncthreads:
// each wave owns 16 edges end-to-end; LDS is per-wave; same-wave DS ordering is
// guaranteed (in-order DS pipe + compiler lgkmcnt). Per-wave LDS union:
//   phase 1: bf16 silu(fc1) tile [16][32] (1 KB)  -- dead after features phase
//   phase 2: X2 transpose [16][ASTR] (5.25 KB)    -- written after sW's last read
// Block LDS = 4*5376 = 21504 B -> 7 blocks/CU = 28 waves (was 29.7 KB -> 5 blocks).
__global__ __launch_bounds__(BLOCK, 4)
void prop_mfma(const float* __restrict__ xn,
               const float* __restrict__ xe_attr,
               const float* __restrict__ W1,
               const float* __restrict__ b1,
               const unsigned short* __restrict__ wsb,
               const int*   __restrict__ esrc,
               const int*   __restrict__ edst,
               float* __restrict__ out,
               int E)
{
    __shared__ __align__(16) unsigned short sU_all[4 * WREGS]; // 21504 B

    const int tid  = threadIdx.x;
    const int lane = tid & 63;
    const int w    = tid >> 6;
    const int l15  = lane & 15;
    const int quad = lane >> 4;
    unsigned short* sU = sU_all + w * WREGS;   // wave-local union region
    unsigned short* sA = sU;                   // [16][ASTR] X2 transpose (phase 2)
    unsigned short* sWb = sU;                  // [16][32] bf16 silu tile (phase 1)

    const long tile = (long)blockIdx.x * 4 + w;
    const long e0   = tile * WTILE;
    if (e0 >= (long)E) return;                 // wave-uniform, no barriers exist
    const int nv = min(WTILE, (int)((long)E - e0));

    const short8* Bp  = reinterpret_cast<const short8*>(wsb);
    const short8* W1p = reinterpret_cast<const short8*>(wsb + FD * FD);

    // ---------------- fc1: W = silu(attr @ W1 + b1) ----------------
    // Lane keeps its fp32 silu values (rows quad*4+r, cols l15 / 16+l15) in
    // registers for the epilogue; bf16 copy goes to LDS for the features read.
    float wreg[2][4];
    {
        int rowA = (int)e0 + ((l15 < nv) ? l15 : 0);
        const float* ar = xe_attr + (size_t)rowA * ATTRD + quad * 8;
        union { short8 v; unsigned short u[8]; } AF0;
        #pragma unroll
        for (int j = 0; j < 8; ++j) AF0.u[j] = bf16h(ar[j]);

        f32x4 c0 = (f32x4){0.f, 0.f, 0.f, 0.f};
        f32x4 c1 = (f32x4){0.f, 0.f, 0.f, 0.f};
        c0 = __builtin_amdgcn_mfma_f32_16x16x32_bf16(AF0.v, W1p[lane],      c0, 0, 0, 0);
        c1 = __builtin_amdgcn_mfma_f32_16x16x32_bf16(AF0.v, W1p[64 + lane], c1, 0, 0, 0);

        float b1a  = b1[l15],            b1b  = b1[16 + l15];
        float w32a = W1[32 * D + l15],   w32b = W1[32 * D + 16 + l15];
        #pragma unroll
        for (int r = 0; r < 4; ++r) {
            int e = quad * 4 + r;
            int rowC = (int)e0 + ((e < nv) ? e : 0);
            float a32 = xe_attr[(size_t)rowC * ATTRD + 32];
            float x0 = c0[r] + b1a + a32 * w32a;
            float x1 = c1[r] + b1b + a32 * w32b;
            float s0 = x0 * __builtin_amdgcn_rcpf(1.0f + __expf(-x0));
            float s1 = x1 * __builtin_amdgcn_rcpf(1.0f + __expf(-x1));
            wreg[0][r] = s0; wreg[1][r] = s1;
            sWb[e * D + l15]      = bf16h(s0);
            sWb[e * D + 16 + l15] = bf16h(s1);
        }
    }

    // ---------------- features: lane owns edge l15, cols quad*8..+8 ----------------
    // A-frags for mm1 chunk ks=q are exactly this lane's feature q values.
    union { short8 v; unsigned short u[8]; } AF[5];
    {
        int ei = (int)e0 + ((l15 < nv) ? l15 : 0);
        int se = esrc[ei], de = edst[ei];
        const float4* xsr = reinterpret_cast<const float4*>(xn + (size_t)se * D + quad * 8);
        const float4* xdr = reinterpret_cast<const float4*>(xn + (size_t)de * D + quad * 8);
        float4 xs0 = xsr[0], xs1 = xsr[1];
        float4 xd0 = xdr[0], xd1 = xdr[1];
        union { short8 v; unsigned short u[8]; } wv8;
        wv8.v = *reinterpret_cast<const short8*>(&sWb[l15 * D + quad * 8]);
        float xs[8] = {xs0.x, xs0.y, xs0.z, xs0.w, xs1.x, xs1.y, xs1.z, xs1.w};
        float xd[8] = {xd0.x, xd0.y, xd0.z, xd0.w, xd1.x, xd1.y, xd1.z, xd1.w};
        #pragma unroll
        for (int c = 0; c < 8; ++c) {
            float wf = bf16tof(wv8.u[c]);
            float g = wf * (xs[c] - xd[c]);
            float a = wf * (xs[c] + xd[c]) * 0.5f;
            AF[0].u[c] = bf16h(fast_tanh(g));
            AF[1].u[c] = bf16h(fast_tanh(a));
            AF[2].u[c] = bf16h(fast_tanh(g * a));
            AF[3].u[c] = bf16h(fast_tanh(g * g));
            AF[4].u[c] = bf16h(fast_tanh(a * a));
        }
    }

    // ---------------- matmul 1: C[nt] (16 edges x 160 cols per wave) ----------------
    f32x4 C[10];
    #pragma unroll
    for (int t = 0; t < 10; ++t) C[t] = (f32x4){0.f, 0.f, 0.f, 0.f};
    #pragma unroll
    for (int ks = 0; ks < NKS; ++ks)
        #pragma unroll
        for (int nt = 0; nt < 10; ++nt)
            C[nt] = __builtin_amdgcn_mfma_f32_16x16x32_bf16(
                AF[ks].v, Bp[(nt * NKS + ks) * 64 + lane], C[nt], 0, 0, 0);

    // ---------------- tv_norm: full row in 16-lane group, shfl-only ----------------
    float mean[4], scale[4];
    #pragma unroll
    for (int r = 0; r < 4; ++r) {
        float s = 0.f, q = 0.f;
        #pragma unroll
        for (int t = 0; t < 10; ++t) { float v = C[t][r]; s += v; q += v * v; }
        #pragma unroll
        for (int m = 1; m < 16; m <<= 1) { s += __shfl_xor(s, m); q += __shfl_xor(q, m); }
        mean[r] = s * (1.0f / FD);
        scale[r] = __builtin_amdgcn_rsqf(q - (float)FD * mean[r] * mean[r] + 1e-3f);
    }

    // ---------------- tanh(tv_norm) -> wave-local LDS transpose (overwrites sWb;
    // safe: DS ops in-order per wave, sWb's last read was the features phase) ----
    #pragma unroll
    for (int t = 0; t < 10; ++t)
        #pragma unroll
        for (int r = 0; r < 4; ++r) {
            float v = fast_tanh((C[t][r] - mean[r]) * scale[r]);
            sA[(quad * 4 + r) * ASTR + t * 16 + l15] = bf16h(v);
        }

    // ---------------- matmul 2 (A from wave-local LDS) ----------------
    #pragma unroll
    for (int t = 0; t < 10; ++t) C[t] = (f32x4){0.f, 0.f, 0.f, 0.f};
    #pragma unroll
    for (int ks = 0; ks < NKS; ++ks) {
        short8 af2 = *reinterpret_cast<const short8*>(&sA[l15 * ASTR + ks * 32 + quad * 8]);
        #pragma unroll
        for (int nt = 0; nt < 10; ++nt)
            C[nt] = __builtin_amdgcn_mfma_f32_16x16x32_bf16(
                af2, Bp[(nt * NKS + ks) * 64 + lane], C[nt], 0, 0, 0);
    }

    // ---------------- epilogue: msg = tile(W,5)*tanh; chunk-reduce; atomics --------
    // W comes from this lane's own fp32 registers (fc1 layout == epilogue layout).
    #pragma unroll
    for (int r = 0; r < 4; ++r) {
        int e = quad * 4 + r;
        if (e >= nv) continue;
        int sd = edst[e0 + e], ss = esrc[e0 + e];
        #pragma unroll
        for (int par = 0; par < 2; ++par) {
            int c = par * 16 + l15;
            float wv = wreg[par][r];
            float m0 = fast_tanh(C[par][r]) * wv;
            float A4 = (fast_tanh(C[par + 2][r]) + fast_tanh(C[par + 4][r])
                      + fast_tanh(C[par + 6][r]) + fast_tanh(C[par + 8][r])) * wv;
            atomicAdd(out + (size_t)sd * D + c, m0 + 0.5f * A4);
            atomicAdd(out + (size_t)ss * D + c, 0.5f * A4 - m0);
        }
    }
}

extern "C" void kernel_launch(void* const* d_in, const int* in_sizes, int n_in,
                              void* d_out, int out_size, void* d_ws, size_t ws_size,
                              hipStream_t stream)
{
    const float* xn   = (const float*)d_in[0];
    const float* attr = (const float*)d_in[1];
    const float* W1   = (const float*)d_in[2];
    const float* b1   = (const float*)d_in[3];
    const float* Wd1  = (const float*)d_in[4];
    const int*   esrc = (const int*)d_in[5];
    const int*   edst = (const int*)d_in[6];
    float* out = (float*)d_out;
    unsigned short* wsb = (unsigned short*)d_ws;   // 26624 bf16 packed B-frags

    const int E = in_sizes[5];

    hipMemsetAsync(d_out, 0, (size_t)out_size * sizeof(float), stream);
    prep_weights<<<(FD * FD + 32 * D + 255) / 256, 256, 0, stream>>>(Wd1, W1, wsb);
    const long tiles = ((long)E + WTILE - 1) / WTILE;
    const int grid = (int)((tiles + 3) / 4);
    prop_mfma<<<grid, BLOCK, 0, stream>>>(xn, attr, W1, b1, wsb, esrc, edst, out, E);
}